// Round 11
// baseline (230.344 us; speedup 1.0000x reference)
//
#include <hip/hip_runtime.h>
#include <hip/hip_bf16.h>

#define CH 128   // IN_C == HID == 128
#define OC 64
#define NBINS 1024   // bucket = dst >> 7 (128 nodes/bucket)
#define NCHK  256    // edge chunks
#define BSH   7

typedef __attribute__((ext_vector_type(4))) float f32x4;
typedef __attribute__((ext_vector_type(8))) float f32x8;
typedef __attribute__((ext_vector_type(8))) short bf16x8;
typedef __attribute__((ext_vector_type(8))) ushort u16x8;

static __device__ __forceinline__ float bf2f(ushort u) {
  return __uint_as_float(((unsigned)u) << 16);
}
static __device__ __forceinline__ ushort f2bf(float f) {
  __hip_bfloat16 h = __float2bfloat16(f);   // RNE
  return *reinterpret_cast<ushort*>(&h);
}
static __device__ __forceinline__ void fma8(float w, u16x8 v, f32x8& a) {
#pragma unroll
  for (int j = 0; j < 8; j++) a[j] = fmaf(w, bf2f((ushort)v[j]), a[j]);
}

// ---------------- merged prep: x->bf16, W transpose->bf16, combined bias ------
__global__ void k_pre(const float* __restrict__ x, ushort* __restrict__ y, int nx,
                      const float* __restrict__ w1, const float* __restrict__ wmu,
                      const float* __restrict__ wls, const float* __restrict__ bmu,
                      const float* __restrict__ bls, ushort* __restrict__ Wt0,
                      ushort* __restrict__ Wt1, float* __restrict__ bc) {
  int gid = blockIdx.x * 256 + threadIdx.x;
  int i = gid * 4;
  if (i < nx) {
    float4 v = *(const float4*)&x[i];
    ushort4 o; o.x = f2bf(v.x); o.y = f2bf(v.y); o.z = f2bf(v.z); o.w = f2bf(v.w);
    *(ushort4*)&y[i] = o;
  }
  if (gid < 16384) {
    int c = gid >> 7, k = gid & 127;
    Wt0[c * 128 + k] = f2bf(w1[k * 128 + c]);
    float v = (c < 64) ? wmu[k * 64 + c] : wls[k * 64 + (c - 64)];
    Wt1[c * 128 + k] = f2bf(v);
    if (gid < 128) bc[gid] = (gid < 64) ? bmu[gid] : bls[gid - 64];
  }
}

// ====== deterministic bucketed CSR build (no global atomics anywhere) ======

// s1: per-chunk histogram of dst buckets; TRANSPOSED store so s2a reads coalesced
__global__ __launch_bounds__(256) void k_s1(const int* __restrict__ dst,
                                            int* __restrict__ bcntT, int ne, int cs) {
  __shared__ int h[NBINS];
  for (int j = threadIdx.x; j < NBINS; j += 256) h[j] = 0;
  __syncthreads();
  int e0 = blockIdx.x * cs, e1 = min(e0 + cs, ne);
  for (int e = e0 + threadIdx.x; e < e1; e += 256)
    atomicAdd(&h[dst[e] >> BSH], 1);
  __syncthreads();
  for (int j = threadIdx.x; j < NBINS; j += 256)
    bcntT[j * NCHK + blockIdx.x] = h[j];
}

// s2a: per-bucket exclusive scan over chunks (fully coalesced)
__global__ __launch_bounds__(256) void k_s2a(const int* __restrict__ bcntT,
                                             int* __restrict__ curT,
                                             int* __restrict__ total) {
  __shared__ int s[NCHK];
  int b = blockIdx.x, t = threadIdx.x;
  int v = bcntT[b * NCHK + t];
  s[t] = v; __syncthreads();
  for (int off = 1; off < NCHK; off <<= 1) {
    int u = (t >= off) ? s[t - off] : 0;
    __syncthreads();
    s[t] += u;
    __syncthreads();
  }
  curT[b * NCHK + t] = s[t] - v;        // exclusive within bucket
  if (t == NCHK - 1) total[b] = s[t];
}

// s2b: exclusive scan of 1024 bucket totals -> base[0..1024]
__global__ void k_s2b(const int* __restrict__ total, int* __restrict__ base) {
  __shared__ int s[256];
  int t = threadIdx.x;
  int loc[4]; int sum = 0;
#pragma unroll
  for (int j = 0; j < 4; j++) { loc[j] = total[t * 4 + j]; sum += loc[j]; }
  s[t] = sum; __syncthreads();
  int own = sum;
  for (int off = 1; off < 256; off <<= 1) {
    int u = (t >= off) ? s[t - off] : 0;
    __syncthreads();
    s[t] += u;
    __syncthreads();
  }
  int excl = s[t] - own;
#pragma unroll
  for (int j = 0; j < 4; j++) { base[t * 4 + j] = excl; excl += loc[j]; }
  if (t == 255) base[NBINS] = excl;
}

// s3: scatter packed (src<<7 | dst&127) into bucket-ordered rec[]
__global__ __launch_bounds__(256) void k_s3(const int* __restrict__ src,
    const int* __restrict__ dst, const int* __restrict__ curT,
    const int* __restrict__ base, unsigned* __restrict__ rec, int ne, int cs) {
  __shared__ int lcur[NBINS];
  int blk = blockIdx.x;
  for (int b = threadIdx.x; b < NBINS; b += 256)
    lcur[b] = curT[b * NCHK + blk] + base[b];
  __syncthreads();
  int e0 = blk * cs, e1 = min(e0 + cs, ne);
  for (int e = e0 + threadIdx.x; e < e1; e += 256) {
    int d = dst[e], sv = src[e];
    int pos = atomicAdd(&lcur[d >> BSH], 1);   // LDS atomic, block-local
    rec[pos] = ((unsigned)sv << BSH) | (unsigned)(d & 127);
  }
}

// s4a: per-bucket degree hist + LDS scan -> deg, rowptr, dinv
__global__ __launch_bounds__(256) void k_s4a(const unsigned* __restrict__ rec,
    const int* __restrict__ base, int* __restrict__ deg, int* __restrict__ rowptr,
    float* __restrict__ dinv, int nn) {
  __shared__ int h[128];
  __shared__ int sc[128];
  int b = blockIdx.x, tid = threadIdx.x;
  if (tid < 128) h[tid] = 0;
  __syncthreads();
  int r0 = base[b], r1 = base[b + 1];
  for (int r = r0 + tid; r < r1; r += 256)
    atomicAdd(&h[rec[r] & 127], 1);
  __syncthreads();
  if (tid < 128) sc[tid] = h[tid];
  __syncthreads();
  for (int off = 1; off < 128; off <<= 1) {
    int v = 0;
    if (tid < 128 && tid >= off) v = sc[tid - off];
    __syncthreads();
    if (tid < 128) sc[tid] += v;
    __syncthreads();
  }
  if (tid < 128) {
    int node = (b << BSH) + tid;
    if (node < nn) {
      int d = h[tid];
      deg[node] = d;
      rowptr[node] = r0 + sc[tid] - d;      // bucket base + exclusive in-bucket
      dinv[node] = rsqrtf((float)(d + 1));  // +1 self-loop
    }
  }
}

// s5: final CSR fill; scattered writes confined to this block's bucket window
__global__ __launch_bounds__(256) void k_s5(const unsigned* __restrict__ rec,
    const int* __restrict__ base, const int* __restrict__ rowptr,
    const int* __restrict__ deg, unsigned* __restrict__ csr, int nn) {
  __shared__ int lcur[128];
  int b = blockIdx.x, tid = threadIdx.x;
  if (tid < 128) {
    int node = (b << BSH) + tid;
    lcur[tid] = (node < nn) ? rowptr[node] : 0;
  }
  __syncthreads();
  int r0 = base[b], r1 = base[b + 1];
  for (int r = r0 + tid; r < r1; r += 256) {
    unsigned rc = rec[r];
    int s = (int)(rc >> BSH);
    int pos = atomicAdd(&lcur[rc & 127], 1);   // LDS atomic, block-local
    unsigned ds = (unsigned)min(deg[s], 32767);
    csr[pos] = (unsigned)s | (ds << 17);
  }
}

// ------- gather core: 16 lanes/node, 8 rows / 12 records in flight -------------
static __device__ __forceinline__ f32x8 gather_core(const ushort* __restrict__ in,
    const int* __restrict__ rowptr, const int* __restrict__ deg,
    const unsigned* __restrict__ csr, const float* __restrict__ dinv,
    int i, int lane16, float& di_out) {
  size_t loff = (size_t)lane16 * 8;
  int beg = rowptr[i];
  int cnt = deg[i];
  float di = dinv[i];
  u16x8 xv = *(const u16x8*)&in[(size_t)i * CH + loff];   // self row, issued early
  f32x8 acc = {0.f, 0.f, 0.f, 0.f, 0.f, 0.f, 0.f, 0.f};

  unsigned rec[12]; u16x8 row[8];
#pragma unroll
  for (int j = 0; j < 12; j++) rec[j] = (j < cnt) ? csr[beg + j] : 0u;
#pragma unroll
  for (int j = 0; j < 8; j++)
    if (j < cnt) row[j] = *(const u16x8*)&in[(size_t)(rec[j] & 0x1FFFFu) * CH + loff];

  int k = 0;
  while (cnt - k > 8) {
    unsigned nrec[4]; u16x8 nrow[4];
#pragma unroll
    for (int j = 0; j < 4; j++)
      nrec[j] = (k + 12 + j < cnt) ? csr[beg + k + 12 + j] : 0u;
#pragma unroll
    for (int j = 0; j < 4; j++)
      nrow[j] = (k + 8 + j < cnt)
              ? *(const u16x8*)&in[(size_t)(rec[8 + j] & 0x1FFFFu) * CH + loff]
              : row[4 + j];
#pragma unroll
    for (int j = 0; j < 4; j++) {
      float w = rsqrtf((float)((rec[j] >> 17) + 1u));
      fma8(w, row[j], acc);
    }
#pragma unroll
    for (int j = 0; j < 8; j++) rec[j] = rec[j + 4];
#pragma unroll
    for (int j = 0; j < 4; j++) { rec[8 + j] = nrec[j]; row[j] = row[4 + j]; row[4 + j] = nrow[j]; }
    k += 4;
  }
#pragma unroll
  for (int j = 0; j < 8; j++) {
    if (k + j < cnt) {
      float w = rsqrtf((float)((rec[j] >> 17) + 1u));
      fma8(w, row[j], acc);
    }
  }
  fma8(di, xv, acc);                 // self loop
  di_out = di;
  return acc;
}

// ---------------- K1: a1 = Agg(x) -> bf16 --------------------------------------
__global__ __launch_bounds__(256) void k_agg0(const ushort* __restrict__ in,
                      ushort* __restrict__ o16,
                      const int* __restrict__ rowptr, const int* __restrict__ deg,
                      const unsigned* __restrict__ csr, const float* __restrict__ dinv,
                      int n) {
  int i = blockIdx.x * 16 + (threadIdx.x >> 4);
  if (i >= n) return;
  int lane = threadIdx.x & 15;
  float di;
  f32x8 acc = gather_core(in, rowptr, deg, csr, dinv, i, lane, di);
  u16x8 o;
#pragma unroll
  for (int j = 0; j < 8; j++) o[j] = (short)f2bf(acc[j] * di);
  *(u16x8*)&o16[(size_t)i * CH + lane * 8] = o;
}

// ---------------- K2: fused dual GEMM p = relu(a1@W1+b1) @ W2 ------------------
// double-buffered hs (1 barrier/tile) + A-prefetch across grid-stride iterations
__global__ __launch_bounds__(256) void k_fused(const ushort* __restrict__ A,
    const ushort* __restrict__ Wt0, const float* __restrict__ b1,
    const ushort* __restrict__ Wt1, ushort* __restrict__ P, int ntiles) {
  __shared__ ushort hs[2][16][136];       // padded: 272B row stride
  int colg = threadIdx.x >> 6;            // wave id = column group
  int lane = threadIdx.x & 63;
  int l15 = lane & 15;
  int lk = (lane >> 4) * 8;
  bf16x8 bfrag1[2][4], bfrag2[2][4];
  float bias1[2];
#pragma unroll
  for (int ct = 0; ct < 2; ct++) {
    int bcol = colg * 32 + ct * 16 + l15;
#pragma unroll
    for (int kt = 0; kt < 4; kt++) {
      bfrag1[ct][kt] = *(const bf16x8*)&Wt0[(size_t)bcol * 128 + kt * 32 + lk];
      bfrag2[ct][kt] = *(const bf16x8*)&Wt1[(size_t)bcol * 128 + kt * 32 + lk];
    }
    bias1[ct] = b1[bcol];
  }
  int G = gridDim.x;
  int t = blockIdx.x;
  int buf = 0;
  bf16x8 af[4];
  if (t < ntiles) {
    const ushort* ap = &A[(size_t)(t * 16 + l15) * CH + lk];
#pragma unroll
    for (int kt = 0; kt < 4; kt++) af[kt] = *(const bf16x8*)&ap[kt * 32];
  }
  for (; t < ntiles; t += G) {
    // prefetch next tile's A while this tile computes
    int tn = t + G;
    bf16x8 afn[4];
    if (tn < ntiles) {
      const ushort* apn = &A[(size_t)(tn * 16 + l15) * CH + lk];
#pragma unroll
      for (int kt = 0; kt < 4; kt++) afn[kt] = *(const bf16x8*)&apn[kt * 32];
    }
    f32x4 a1[2] = {{0.f, 0.f, 0.f, 0.f}, {0.f, 0.f, 0.f, 0.f}};
#pragma unroll
    for (int ct = 0; ct < 2; ct++)
#pragma unroll
      for (int kt = 0; kt < 4; kt++)
        a1[ct] = __builtin_amdgcn_mfma_f32_16x16x32_bf16(af[kt], bfrag1[ct][kt], a1[ct], 0, 0, 0);
#pragma unroll
    for (int ct = 0; ct < 2; ct++) {
      int col = colg * 32 + ct * 16 + l15;
#pragma unroll
      for (int r = 0; r < 4; r++)
        hs[buf][(lane >> 4) * 4 + r][col] = f2bf(fmaxf(a1[ct][r] + bias1[ct], 0.f));
    }
    __syncthreads();   // hs[buf] complete; rewrite of this buffer happens 2 iters
                       // later, ordered after all reads via the NEXT barrier
    bf16x8 af2[4];
#pragma unroll
    for (int kt = 0; kt < 4; kt++) af2[kt] = *(const bf16x8*)&hs[buf][l15][kt * 32 + lk];
    f32x4 a2[2] = {{0.f, 0.f, 0.f, 0.f}, {0.f, 0.f, 0.f, 0.f}};
#pragma unroll
    for (int ct = 0; ct < 2; ct++)
#pragma unroll
      for (int kt = 0; kt < 4; kt++)
        a2[ct] = __builtin_amdgcn_mfma_f32_16x16x32_bf16(af2[kt], bfrag2[ct][kt], a2[ct], 0, 0, 0);
#pragma unroll
    for (int ct = 0; ct < 2; ct++) {
      int col = colg * 32 + ct * 16 + l15;
#pragma unroll
      for (int r = 0; r < 4; r++) {
        int node = t * 16 + (lane >> 4) * 4 + r;
        P[(size_t)node * CH + col] = f2bf(a2[ct][r]);
      }
    }
    buf ^= 1;
#pragma unroll
    for (int kt = 0; kt < 4; kt++) af[kt] = afn[kt];
  }
}

// ---------------- K3: agg(p) + bias -> mu/logstd fp32 --------------------------
__global__ __launch_bounds__(256) void k_aggout(const ushort* __restrict__ in,
                      float* __restrict__ oA, float* __restrict__ oB,
                      const float* __restrict__ bc,
                      const int* __restrict__ rowptr, const int* __restrict__ deg,
                      const unsigned* __restrict__ csr, const float* __restrict__ dinv,
                      int n) {
  int i = blockIdx.x * 16 + (threadIdx.x >> 4);
  if (i >= n) return;
  int lane = threadIdx.x & 15;
  float di;
  f32x8 acc = gather_core(in, rowptr, deg, csr, dinv, i, lane, di);
  f32x8 b8 = *(const f32x8*)&bc[lane * 8];
  f32x8 o;
#pragma unroll
  for (int j = 0; j < 8; j++) o[j] = acc[j] * di + b8[j];
  if (lane < 8) *(f32x8*)&oA[(size_t)i * OC + lane * 8] = o;
  else          *(f32x8*)&oB[(size_t)i * OC + (lane - 8) * 8] = o;
}

// ---------------- launch ----------------

extern "C" void kernel_launch(void* const* d_in, const int* in_sizes, int n_in,
                              void* d_out, int out_size, void* d_ws, size_t ws_size,
                              hipStream_t stream) {
  const float* x   = (const float*)d_in[0];
  const int*   ei  = (const int*)d_in[1];
  const float* w1  = (const float*)d_in[2];
  const float* b1  = (const float*)d_in[3];
  const float* wmu = (const float*)d_in[4];
  const float* bmu = (const float*)d_in[5];
  const float* wls = (const float*)d_in[6];
  const float* bls = (const float*)d_in[7];
  float* out = (float*)d_out;

  const int nn = in_sizes[0] / CH;     // 100000
  const int ne = in_sizes[1] / 2;      // 1600000
  const int* srcp = ei;
  const int* dstp = ei + ne;

  ushort*   B0   = (ushort*)d_ws;                     // [nn,128] bf16 x, later p
  ushort*   B1   = B0 + (size_t)nn * CH;              // [nn,128] bf16 a1 — aliased below
  unsigned* csr  = (unsigned*)(B1 + (size_t)nn * CH); // [ne] packed src|deg<<17
  int*      deg  = (int*)(csr + ne);                  // [nn]
  int*      rowptr = deg + nn;                        // [nn]
  float*    dinv = (float*)(rowptr + nn);             // [nn]
  ushort*   Wt0  = (ushort*)(dinv + nn);              // [128*128] bf16 (w1^T)
  ushort*   Wt1  = Wt0 + 128 * 128;                   // [128*128] bf16 (wmu|wls ^T)
  float*    bc   = (float*)(Wt1 + 128 * 128);         // [128] combined head bias

  // CSR-build temporaries aliased into B1 (dead before k_agg0 writes B1)
  unsigned* rec  = (unsigned*)B1;                     // [ne] packed src<<7|dst&127
  int*      bcntT= (int*)(rec + ne);                  // [NBINS*NCHK] transposed
  int*      curT = bcntT + NBINS * NCHK;              // [NBINS*NCHK]
  int*      btot = curT + NBINS * NCHK;               // [NBINS]
  int*      bbase= btot + NBINS;                      // [NBINS+1]

  const int NBUK = (nn + 127) >> BSH;  // 782
  const int cs = (ne + NCHK - 1) / NCHK;

  k_s1 <<<NCHK, 256, 0, stream>>>(dstp, bcntT, ne, cs);
  k_s2a<<<NBINS, NCHK, 0, stream>>>(bcntT, curT, btot);
  k_s2b<<<1, 256, 0, stream>>>(btot, bbase);
  k_s3 <<<NCHK, 256, 0, stream>>>(srcp, dstp, curT, bbase, rec, ne, cs);
  k_s4a<<<NBUK, 256, 0, stream>>>(rec, bbase, deg, rowptr, dinv, nn);
  k_s5 <<<NBUK, 256, 0, stream>>>(rec, bbase, rowptr, deg, csr, nn);
  k_pre<<<((nn * CH / 4) + 255) / 256, 256, 0, stream>>>(x, B0, nn * CH,
                                 w1, wmu, wls, bmu, bls, Wt0, Wt1, bc);

  const int AB = (nn + 15) / 16;   // 6250
  const int ntiles = nn / 16;      // 6250

  // a1 = Agg(x) -> B1
  k_agg0<<<AB, 256, 0, stream>>>(B0, B1, rowptr, deg, csr, dinv, nn);
  // p = relu(a1@W1+b1) @ [wmu|wls] -> B0
  k_fused<<<2048, 256, 0, stream>>>(B1, Wt0, b1, Wt1, B0, ntiles);
  // [mu|logstd] = Agg(p) + bias -> d_out
  k_aggout<<<AB, 256, 0, stream>>>(B0, out, out + (size_t)nn * OC, bc,
                                   rowptr, deg, csr, dinv, nn);
}

// Round 12
// 215.680 us; speedup vs baseline: 1.0680x; 1.0680x over previous
//
#include <hip/hip_runtime.h>
#include <hip/hip_bf16.h>

#define CH 128   // IN_C == HID == 128
#define OC 64
#define NBINS 1024   // bucket = dst >> 7 (128 nodes/bucket)
#define NCHK  256    // edge chunks
#define BSH   7

typedef __attribute__((ext_vector_type(4))) float f32x4;
typedef __attribute__((ext_vector_type(8))) float f32x8;
typedef __attribute__((ext_vector_type(8))) short bf16x8;
typedef __attribute__((ext_vector_type(8))) ushort u16x8;

static __device__ __forceinline__ float bf2f(ushort u) {
  return __uint_as_float(((unsigned)u) << 16);
}
static __device__ __forceinline__ ushort f2bf(float f) {
  __hip_bfloat16 h = __float2bfloat16(f);   // RNE
  return *reinterpret_cast<ushort*>(&h);
}
static __device__ __forceinline__ void fma8(float w, u16x8 v, f32x8& a) {
#pragma unroll
  for (int j = 0; j < 8; j++) a[j] = fmaf(w, bf2f((ushort)v[j]), a[j]);
}

// ---------------- merged prep: x->bf16, W transpose->bf16, combined bias ------
__global__ void k_pre(const float* __restrict__ x, ushort* __restrict__ y, int nx,
                      const float* __restrict__ w1, const float* __restrict__ wmu,
                      const float* __restrict__ wls, const float* __restrict__ bmu,
                      const float* __restrict__ bls, ushort* __restrict__ Wt0,
                      ushort* __restrict__ Wt1, float* __restrict__ bc) {
  int gid = blockIdx.x * 256 + threadIdx.x;
  int i = gid * 4;
  if (i < nx) {
    float4 v = *(const float4*)&x[i];
    ushort4 o; o.x = f2bf(v.x); o.y = f2bf(v.y); o.z = f2bf(v.z); o.w = f2bf(v.w);
    *(ushort4*)&y[i] = o;
  }
  if (gid < 16384) {
    int c = gid >> 7, k = gid & 127;
    Wt0[c * 128 + k] = f2bf(w1[k * 128 + c]);
    float v = (c < 64) ? wmu[k * 64 + c] : wls[k * 64 + (c - 64)];
    Wt1[c * 128 + k] = f2bf(v);
    if (gid < 128) bc[gid] = (gid < 64) ? bmu[gid] : bls[gid - 64];
  }
}

// ====== deterministic bucketed CSR build (no global atomics anywhere) ======

// s1: per-chunk histogram of dst buckets; TRANSPOSED store so s2a reads coalesced
__global__ __launch_bounds__(256) void k_s1(const int* __restrict__ dst,
                                            int* __restrict__ bcntT, int ne, int cs) {
  __shared__ int h[NBINS];
  for (int j = threadIdx.x; j < NBINS; j += 256) h[j] = 0;
  __syncthreads();
  int e0 = blockIdx.x * cs, e1 = min(e0 + cs, ne);
  for (int e = e0 + threadIdx.x; e < e1; e += 256)
    atomicAdd(&h[dst[e] >> BSH], 1);
  __syncthreads();
  for (int j = threadIdx.x; j < NBINS; j += 256)
    bcntT[j * NCHK + blockIdx.x] = h[j];
}

// s2a: per-bucket exclusive scan over chunks (fully coalesced)
__global__ __launch_bounds__(256) void k_s2a(const int* __restrict__ bcntT,
                                             int* __restrict__ curT,
                                             int* __restrict__ total) {
  __shared__ int s[NCHK];
  int b = blockIdx.x, t = threadIdx.x;
  int v = bcntT[b * NCHK + t];
  s[t] = v; __syncthreads();
  for (int off = 1; off < NCHK; off <<= 1) {
    int u = (t >= off) ? s[t - off] : 0;
    __syncthreads();
    s[t] += u;
    __syncthreads();
  }
  curT[b * NCHK + t] = s[t] - v;        // exclusive within bucket
  if (t == NCHK - 1) total[b] = s[t];
}

// s2b: exclusive scan of 1024 bucket totals -> base[0..1024]
__global__ void k_s2b(const int* __restrict__ total, int* __restrict__ base) {
  __shared__ int s[256];
  int t = threadIdx.x;
  int loc[4]; int sum = 0;
#pragma unroll
  for (int j = 0; j < 4; j++) { loc[j] = total[t * 4 + j]; sum += loc[j]; }
  s[t] = sum; __syncthreads();
  int own = sum;
  for (int off = 1; off < 256; off <<= 1) {
    int u = (t >= off) ? s[t - off] : 0;
    __syncthreads();
    s[t] += u;
    __syncthreads();
  }
  int excl = s[t] - own;
#pragma unroll
  for (int j = 0; j < 4; j++) { base[t * 4 + j] = excl; excl += loc[j]; }
  if (t == 255) base[NBINS] = excl;
}

// s3: scatter packed (src<<7 | dst&127) into bucket-ordered rec[]
__global__ __launch_bounds__(256) void k_s3(const int* __restrict__ src,
    const int* __restrict__ dst, const int* __restrict__ curT,
    const int* __restrict__ base, unsigned* __restrict__ rec, int ne, int cs) {
  __shared__ int lcur[NBINS];
  int blk = blockIdx.x;
  for (int b = threadIdx.x; b < NBINS; b += 256)
    lcur[b] = curT[b * NCHK + blk] + base[b];
  __syncthreads();
  int e0 = blk * cs, e1 = min(e0 + cs, ne);
  for (int e = e0 + threadIdx.x; e < e1; e += 256) {
    int d = dst[e], sv = src[e];
    int pos = atomicAdd(&lcur[d >> BSH], 1);   // LDS atomic, block-local
    rec[pos] = ((unsigned)sv << BSH) | (unsigned)(d & 127);
  }
}

// s4a: per-bucket degree hist + LDS scan -> deg, rowptr, dinv
__global__ __launch_bounds__(256) void k_s4a(const unsigned* __restrict__ rec,
    const int* __restrict__ base, int* __restrict__ deg, int* __restrict__ rowptr,
    float* __restrict__ dinv, int nn) {
  __shared__ int h[128];
  __shared__ int sc[128];
  int b = blockIdx.x, tid = threadIdx.x;
  if (tid < 128) h[tid] = 0;
  __syncthreads();
  int r0 = base[b], r1 = base[b + 1];
  for (int r = r0 + tid; r < r1; r += 256)
    atomicAdd(&h[rec[r] & 127], 1);
  __syncthreads();
  if (tid < 128) sc[tid] = h[tid];
  __syncthreads();
  for (int off = 1; off < 128; off <<= 1) {
    int v = 0;
    if (tid < 128 && tid >= off) v = sc[tid - off];
    __syncthreads();
    if (tid < 128) sc[tid] += v;
    __syncthreads();
  }
  if (tid < 128) {
    int node = (b << BSH) + tid;
    if (node < nn) {
      int d = h[tid];
      deg[node] = d;
      rowptr[node] = r0 + sc[tid] - d;      // bucket base + exclusive in-bucket
      dinv[node] = rsqrtf((float)(d + 1));  // +1 self-loop
    }
  }
}

// s5: final CSR fill; scattered writes confined to this block's bucket window
__global__ __launch_bounds__(256) void k_s5(const unsigned* __restrict__ rec,
    const int* __restrict__ base, const int* __restrict__ rowptr,
    const int* __restrict__ deg, unsigned* __restrict__ csr, int nn) {
  __shared__ int lcur[128];
  int b = blockIdx.x, tid = threadIdx.x;
  if (tid < 128) {
    int node = (b << BSH) + tid;
    lcur[tid] = (node < nn) ? rowptr[node] : 0;
  }
  __syncthreads();
  int r0 = base[b], r1 = base[b + 1];
  for (int r = r0 + tid; r < r1; r += 256) {
    unsigned rc = rec[r];
    int s = (int)(rc >> BSH);
    int pos = atomicAdd(&lcur[rc & 127], 1);   // LDS atomic, block-local
    unsigned ds = (unsigned)min(deg[s], 32767);
    csr[pos] = (unsigned)s | (ds << 17);
  }
}

// ---------------- gather core: 16 lanes/node, 4-deep pipeline (proven r5-r10) ---
static __device__ __forceinline__ f32x8 gather_core(const ushort* __restrict__ in,
    const int* __restrict__ rowptr, const int* __restrict__ deg,
    const unsigned* __restrict__ csr, const float* __restrict__ dinv,
    int i, int lane16, float& di_out) {
  size_t loff = (size_t)lane16 * 8;
  int beg = rowptr[i];
  int cnt = deg[i];
  float di = dinv[i];
  u16x8 xv = *(const u16x8*)&in[(size_t)i * CH + loff];   // self row, issued early
  f32x8 acc = {0.f, 0.f, 0.f, 0.f, 0.f, 0.f, 0.f, 0.f};

  unsigned rec[8]; u16x8 row[4];
#pragma unroll
  for (int j = 0; j < 8; j++) rec[j] = (j < cnt) ? csr[beg + j] : 0u;
#pragma unroll
  for (int j = 0; j < 4; j++)
    if (j < cnt) row[j] = *(const u16x8*)&in[(size_t)(rec[j] & 0x1FFFFu) * CH + loff];

  int k = 0;
  while (cnt - k > 4) {
    unsigned nrec[4]; u16x8 nrow[4];
#pragma unroll
    for (int j = 0; j < 4; j++)
      nrec[j] = (k + 8 + j < cnt) ? csr[beg + k + 8 + j] : 0u;
#pragma unroll
    for (int j = 0; j < 4; j++)
      nrow[j] = (k + 4 + j < cnt)
              ? *(const u16x8*)&in[(size_t)(rec[4 + j] & 0x1FFFFu) * CH + loff]
              : row[j];
#pragma unroll
    for (int j = 0; j < 4; j++) {
      float w = rsqrtf((float)((rec[j] >> 17) + 1u));
      fma8(w, row[j], acc);
    }
#pragma unroll
    for (int j = 0; j < 4; j++) { rec[j] = rec[4 + j]; rec[4 + j] = nrec[j]; row[j] = nrow[j]; }
    k += 4;
  }
#pragma unroll
  for (int j = 0; j < 4; j++) {
    if (k + j < cnt) {
      float w = rsqrtf((float)((rec[j] >> 17) + 1u));
      fma8(w, row[j], acc);
    }
  }
  fma8(di, xv, acc);                 // self loop
  di_out = di;
  return acc;
}

// ---------------- K1: a1 = Agg(x) -> bf16 --------------------------------------
__global__ __launch_bounds__(256) void k_agg0(const ushort* __restrict__ in,
                      ushort* __restrict__ o16,
                      const int* __restrict__ rowptr, const int* __restrict__ deg,
                      const unsigned* __restrict__ csr, const float* __restrict__ dinv,
                      int n) {
  int i = blockIdx.x * 16 + (threadIdx.x >> 4);
  if (i >= n) return;
  int lane = threadIdx.x & 15;
  float di;
  f32x8 acc = gather_core(in, rowptr, deg, csr, dinv, i, lane, di);
  u16x8 o;
#pragma unroll
  for (int j = 0; j < 8; j++) o[j] = (short)f2bf(acc[j] * di);
  *(u16x8*)&o16[(size_t)i * CH + lane * 8] = o;
}

// ---------------- K2: fused dual GEMM p = relu(a1@W1+b1) @ W2 ------------------
__global__ __launch_bounds__(256) void k_fused(const ushort* __restrict__ A,
    const ushort* __restrict__ Wt0, const float* __restrict__ b1,
    const ushort* __restrict__ Wt1, ushort* __restrict__ P, int ntiles) {
  __shared__ ushort hs[16][136];          // padded: 272B row stride (16B-aligned)
  int colg = threadIdx.x >> 6;            // wave id = column group
  int lane = threadIdx.x & 63;
  int l15 = lane & 15;
  int lk = (lane >> 4) * 8;
  bf16x8 bfrag1[2][4], bfrag2[2][4];
  float bias1[2];
#pragma unroll
  for (int ct = 0; ct < 2; ct++) {
    int bcol = colg * 32 + ct * 16 + l15;
#pragma unroll
    for (int kt = 0; kt < 4; kt++) {
      bfrag1[ct][kt] = *(const bf16x8*)&Wt0[(size_t)bcol * 128 + kt * 32 + lk];
      bfrag2[ct][kt] = *(const bf16x8*)&Wt1[(size_t)bcol * 128 + kt * 32 + lk];
    }
    bias1[ct] = b1[bcol];
  }
  for (int t = blockIdx.x; t < ntiles; t += gridDim.x) {
    const ushort* ap = &A[(size_t)(t * 16 + l15) * CH + lk];
    bf16x8 af[4];
#pragma unroll
    for (int kt = 0; kt < 4; kt++) af[kt] = *(const bf16x8*)&ap[kt * 32];
    f32x4 a1[2] = {{0.f, 0.f, 0.f, 0.f}, {0.f, 0.f, 0.f, 0.f}};
#pragma unroll
    for (int ct = 0; ct < 2; ct++)
#pragma unroll
      for (int kt = 0; kt < 4; kt++)
        a1[ct] = __builtin_amdgcn_mfma_f32_16x16x32_bf16(af[kt], bfrag1[ct][kt], a1[ct], 0, 0, 0);
#pragma unroll
    for (int ct = 0; ct < 2; ct++) {
      int col = colg * 32 + ct * 16 + l15;
#pragma unroll
      for (int r = 0; r < 4; r++)
        hs[(lane >> 4) * 4 + r][col] = f2bf(fmaxf(a1[ct][r] + bias1[ct], 0.f));
    }
    __syncthreads();
    bf16x8 af2[4];
#pragma unroll
    for (int kt = 0; kt < 4; kt++) af2[kt] = *(const bf16x8*)&hs[l15][kt * 32 + lk];
    f32x4 a2[2] = {{0.f, 0.f, 0.f, 0.f}, {0.f, 0.f, 0.f, 0.f}};
#pragma unroll
    for (int ct = 0; ct < 2; ct++)
#pragma unroll
      for (int kt = 0; kt < 4; kt++)
        a2[ct] = __builtin_amdgcn_mfma_f32_16x16x32_bf16(af2[kt], bfrag2[ct][kt], a2[ct], 0, 0, 0);
#pragma unroll
    for (int ct = 0; ct < 2; ct++) {
      int col = colg * 32 + ct * 16 + l15;
#pragma unroll
      for (int r = 0; r < 4; r++) {
        int node = t * 16 + (lane >> 4) * 4 + r;
        P[(size_t)node * CH + col] = f2bf(a2[ct][r]);
      }
    }
    __syncthreads();   // protect hs before next iteration's writes
  }
}

// ---------------- K3: agg(p) + bias -> mu/logstd fp32 --------------------------
__global__ __launch_bounds__(256) void k_aggout(const ushort* __restrict__ in,
                      float* __restrict__ oA, float* __restrict__ oB,
                      const float* __restrict__ bc,
                      const int* __restrict__ rowptr, const int* __restrict__ deg,
                      const unsigned* __restrict__ csr, const float* __restrict__ dinv,
                      int n) {
  int i = blockIdx.x * 16 + (threadIdx.x >> 4);
  if (i >= n) return;
  int lane = threadIdx.x & 15;
  float di;
  f32x8 acc = gather_core(in, rowptr, deg, csr, dinv, i, lane, di);
  f32x8 b8 = *(const f32x8*)&bc[lane * 8];
  f32x8 o;
#pragma unroll
  for (int j = 0; j < 8; j++) o[j] = acc[j] * di + b8[j];
  if (lane < 8) *(f32x8*)&oA[(size_t)i * OC + lane * 8] = o;
  else          *(f32x8*)&oB[(size_t)i * OC + (lane - 8) * 8] = o;
}

// ---------------- launch ----------------

extern "C" void kernel_launch(void* const* d_in, const int* in_sizes, int n_in,
                              void* d_out, int out_size, void* d_ws, size_t ws_size,
                              hipStream_t stream) {
  const float* x   = (const float*)d_in[0];
  const int*   ei  = (const int*)d_in[1];
  const float* w1  = (const float*)d_in[2];
  const float* b1  = (const float*)d_in[3];
  const float* wmu = (const float*)d_in[4];
  const float* bmu = (const float*)d_in[5];
  const float* wls = (const float*)d_in[6];
  const float* bls = (const float*)d_in[7];
  float* out = (float*)d_out;

  const int nn = in_sizes[0] / CH;     // 100000
  const int ne = in_sizes[1] / 2;      // 1600000
  const int* srcp = ei;
  const int* dstp = ei + ne;

  ushort*   B0   = (ushort*)d_ws;                     // [nn,128] bf16 x, later p
  ushort*   B1   = B0 + (size_t)nn * CH;              // [nn,128] bf16 a1 — aliased below
  unsigned* csr  = (unsigned*)(B1 + (size_t)nn * CH); // [ne] packed src|deg<<17
  int*      deg  = (int*)(csr + ne);                  // [nn]
  int*      rowptr = deg + nn;                        // [nn]
  float*    dinv = (float*)(rowptr + nn);             // [nn]
  ushort*   Wt0  = (ushort*)(dinv + nn);              // [128*128] bf16 (w1^T)
  ushort*   Wt1  = Wt0 + 128 * 128;                   // [128*128] bf16 (wmu|wls ^T)
  float*    bc   = (float*)(Wt1 + 128 * 128);         // [128] combined head bias

  // CSR-build temporaries aliased into B1 (dead before k_agg0 writes B1)
  unsigned* rec  = (unsigned*)B1;                     // [ne] packed src<<7|dst&127
  int*      bcntT= (int*)(rec + ne);                  // [NBINS*NCHK] transposed
  int*      curT = bcntT + NBINS * NCHK;              // [NBINS*NCHK]
  int*      btot = curT + NBINS * NCHK;               // [NBINS]
  int*      bbase= btot + NBINS;                      // [NBINS+1]

  const int NBUK = (nn + 127) >> BSH;  // 782
  const int cs = (ne + NCHK - 1) / NCHK;

  k_s1 <<<NCHK, 256, 0, stream>>>(dstp, bcntT, ne, cs);
  k_s2a<<<NBINS, NCHK, 0, stream>>>(bcntT, curT, btot);
  k_s2b<<<1, 256, 0, stream>>>(btot, bbase);
  k_s3 <<<NCHK, 256, 0, stream>>>(srcp, dstp, curT, bbase, rec, ne, cs);
  k_s4a<<<NBUK, 256, 0, stream>>>(rec, bbase, deg, rowptr, dinv, nn);
  k_s5 <<<NBUK, 256, 0, stream>>>(rec, bbase, rowptr, deg, csr, nn);
  k_pre<<<((nn * CH / 4) + 255) / 256, 256, 0, stream>>>(x, B0, nn * CH,
                                 w1, wmu, wls, bmu, bls, Wt0, Wt1, bc);

  const int AB = (nn + 15) / 16;   // 6250
  const int ntiles = nn / 16;      // 6250

  // a1 = Agg(x) -> B1
  k_agg0<<<AB, 256, 0, stream>>>(B0, B1, rowptr, deg, csr, dinv, nn);
  // p = relu(a1@W1+b1) @ [wmu|wls] -> B0
  k_fused<<<1024, 256, 0, stream>>>(B1, Wt0, b1, Wt1, B0, ntiles);
  // [mu|logstd] = Agg(p) + bias -> d_out
  k_aggout<<<AB, 256, 0, stream>>>(B0, out, out + (size_t)nn * OC, bc,
                                   rowptr, deg, csr, dinv, nn);
}